// Round 2
// baseline (130.414 us; speedup 1.0000x reference)
//
#include <hip/hip_runtime.h>

#define T_SEQ 4096
#define NH    12

typedef _Float16 half8  __attribute__((ext_vector_type(8)));
typedef _Float16 half4  __attribute__((ext_vector_type(4)));
typedef float    floatx4 __attribute__((ext_vector_type(4)));

// Sliding-window attention, window [gq-128, gq+128) ∩ [0,T).
// One WG = 128 query rows; 8 waves * 16 rows; grid = 768 = exactly 3 WG/CU
// (48 KB LDS * 3 = 144 KB; __launch_bounds__(512,6) caps VGPR for 6 waves/SIMD).
// Swapped QK^T (mfma(K,Q) -> S^T in regs): 4 consecutive keys per acc quad ->
// P spills as 4x ds_write_b64 instead of 16x ds_write_b16. Row-sum l folded
// into the exp pass (f32 adds) + epilogue shuffle; no ones-MFMA.
// Single prefetch slot, commit-first; raw barrier (lgkmcnt only, NO vmcnt
// drain) so prefetch loads stay in flight across it. setprio(1) on MFMA.
__global__ __launch_bounds__(512, 6) void local_attn_f16(
    const float* __restrict__ Qg, const float* __restrict__ Kg,
    const float* __restrict__ Vg, float* __restrict__ Og)
{
    // XOR-swizzled 16B-block layouts: element (row,x) at
    // row*64 + (((x>>3) ^ (row&7))*8) + (x&7)   [halves]
    __shared__ _Float16 Ks[2][64 * 64];  // K chunk  [key][d]
    __shared__ _Float16 Vt[2][64 * 64];  // V^T      [d][key]
    __shared__ _Float16 Ps[8][16 * 64];  // per-wave P [qrow][key]

    const int t    = threadIdx.x;
    const int w    = t >> 6;        // wave id 0..7
    const int lane = t & 63;
    const int n    = lane & 15;     // MFMA 16-index
    const int qd   = lane >> 4;     // quad 0..3

    // XCD-aware swizzle: 4 consecutive tiles per XCD (wgid%8 == bx&7)
    const int bx   = blockIdx.x;    // 0..31
    const int tile = ((bx & 7) << 2) | (bx >> 3);
    const int s    = tile << 7;     // query tile start (128 rows)
    const size_t plane = (size_t)(blockIdx.z * NH + blockIdx.y) * (size_t)(T_SEQ * 64);

    const float* Qp = Qg + plane;
    const float* Kp = Kg + plane;
    const float* Vp = Vg + plane;
    float*       Op = Og + plane;

    // staging thread mappings (64-key chunk staged by all 512 threads)
    const int kr  = t >> 3;         // K row 0..63
    const int kbi = t & 7;          // 8-float block within row
    const int vd  = t & 63;         // V^T: this thread owns column d
    const int vjb = t >> 6;         // 8-key range per wave

    // ---- prefetch chunk data (single slot; commit-first keeps 1 slot live) ----
    floatx4 kp0, kp1;
    float   vp[8];

    auto prefetchKV = [&](int c) {
        const int gk0 = s - 128 + 64 * c;
        const float* kb = Kp + (size_t)(gk0 + kr) * 64 + kbi * 8;
        kp0 = *(const floatx4*)kb;
        kp1 = *(const floatx4*)(kb + 4);
        const float* vb = Vp + (size_t)(gk0 + vjb * 8) * 64 + vd;
        #pragma unroll
        for (int j = 0; j < 8; ++j)          // 8x coalesced 256B/wave
            vp[j] = vb[(size_t)j * 64];
    };

    auto commitKV = [&](int buf) {
        half8 hk, hv;
        #pragma unroll
        for (int i = 0; i < 4; ++i) {
            hk[i]     = (_Float16)kp0[i];
            hk[i + 4] = (_Float16)kp1[i];
        }
        #pragma unroll
        for (int i = 0; i < 8; ++i)
            hv[i] = (_Float16)vp[i];
        *(half8*)&Ks[buf][kr * 64 + (kbi ^ (kr & 7)) * 8] = hk;
        *(half8*)&Vt[buf][vd * 64 + (vjb ^ (vd & 7)) * 8] = hv;
    };

    // ---- preload Q B-fragments, scaled by log2(e)/sqrt(64) ----
    prefetchKV((s == 0) ? 2 : 0);   // issue chunk-0 loads before Q loads
    half8 qf[2];
    {
        const float* qptr = Qp + (size_t)(s + 16 * w + n) * 64 + qd * 8;
        const float qscale = 0.125f * 1.44269504088896340736f;
        #pragma unroll
        for (int ks = 0; ks < 2; ++ks) {
            floatx4 a = *(const floatx4*)(qptr + 32 * ks);
            floatx4 b = *(const floatx4*)(qptr + 32 * ks + 4);
            half8 h;
            #pragma unroll
            for (int i = 0; i < 4; ++i) {
                h[i]     = (_Float16)(a[i] * qscale);
                h[i + 4] = (_Float16)(b[i] * qscale);
            }
            qf[ks] = h;
        }
    }

    floatx4 Oacc[4] = {{0.f,0.f,0.f,0.f},{0.f,0.f,0.f,0.f},
                       {0.f,0.f,0.f,0.f},{0.f,0.f,0.f,0.f}};
    float Lsum = 0.f;

    // Raw barrier: publish LDS writes, do NOT drain vmcnt (T4).
    #define WG_BARRIER() do {                                        \
        __builtin_amdgcn_sched_barrier(0);                           \
        asm volatile("s_waitcnt lgkmcnt(0)" ::: "memory");           \
        __builtin_amdgcn_s_barrier();                                \
        __builtin_amdgcn_sched_barrier(0);                           \
    } while (0)

    _Float16* Pw = &Ps[w][0];

    auto compute = [&](int buf, int c) {
        const int wbase = 16 * w;
        // wave-uniform full-mask skip: waves 4-7 skip c=0, waves 0-3 skip c=5
        if (64 * c + 63 < wbase || 64 * c >= wbase + 271) return;

        // ---- S^T = K (Q*log2e)^T : 8 MFMAs; S^T[key=16tt+qd*4+rg][query=n] ----
        floatx4 acc[4] = {{0.f,0.f,0.f,0.f},{0.f,0.f,0.f,0.f},
                          {0.f,0.f,0.f,0.f},{0.f,0.f,0.f,0.f}};
        __builtin_amdgcn_s_setprio(1);
        #pragma unroll
        for (int ks = 0; ks < 2; ++ks) {
            #pragma unroll
            for (int tt = 0; tt < 4; ++tt) {
                const int key = tt * 16 + n;
                half8 kf = *(const half8*)&Ks[buf][key * 64 + (((ks << 2) | qd) ^ (key & 7)) * 8];
                acc[tt] = __builtin_amdgcn_mfma_f32_16x16x32_f16(kf, qf[ks], acc[tt], 0, 0, 0);
            }
        }
        __builtin_amdgcn_s_setprio(0);

        // ---- window masks: key kk valid iff 0 <= 64c+kk-qloc < 256 ----
        const int qloc = wbase + n;
        if (64 * c < wbase + 16) {              // lower edge crosses this wave
            const int tLo = qloc - 64 * c;      // kk < tLo -> invalid
            #pragma unroll
            for (int tt = 0; tt < 4; ++tt)
                #pragma unroll
                for (int rg = 0; rg < 4; ++rg)
                    if (tt * 16 + qd * 4 + rg < tLo) acc[tt][rg] = -1e30f;
        }
        if (64 * c >= wbase + 193) {            // upper edge crosses this wave
            const int tHi = qloc + 256 - 64 * c; // kk >= tHi -> invalid
            #pragma unroll
            for (int tt = 0; tt < 4; ++tt)
                #pragma unroll
                for (int rg = 0; rg < 4; ++rg)
                    if (tt * 16 + qd * 4 + rg >= tHi) acc[tt][rg] = -1e30f;
        }

        // ---- P = exp2(S'), accumulate row-sum, pack 4 keys -> ds_write_b64 ----
        #pragma unroll
        for (int tt = 0; tt < 4; ++tt) {
            float p0, p1, p2, p3;
            asm("v_exp_f32 %0, %1" : "=v"(p0) : "v"(acc[tt][0]));
            asm("v_exp_f32 %0, %1" : "=v"(p1) : "v"(acc[tt][1]));
            asm("v_exp_f32 %0, %1" : "=v"(p2) : "v"(acc[tt][2]));
            asm("v_exp_f32 %0, %1" : "=v"(p3) : "v"(acc[tt][3]));
            Lsum += (p0 + p1) + (p2 + p3);
            half4 pk;
            pk[0] = (_Float16)p0; pk[1] = (_Float16)p1;
            pk[2] = (_Float16)p2; pk[3] = (_Float16)p3;
            // keys k0=16tt+4qd..+3, query n: contiguous 8B (block 2tt+(qd>>1))
            *(half4*)&Pw[n * 64 + ((2 * tt + (qd >> 1)) ^ (n & 7)) * 8 + (qd & 1) * 4] = pk;
        }

        // Ps is per-wave: drain DS writes only, no WG barrier.
        asm volatile("s_waitcnt lgkmcnt(0)" ::: "memory");

        // ---- O += P V ----
        __builtin_amdgcn_s_setprio(1);
        #pragma unroll
        for (int js = 0; js < 2; ++js) {
            half8 pf = *(const half8*)&Pw[n * 64 + (((js << 2) | qd) ^ (n & 7)) * 8];
            #pragma unroll
            for (int tt = 0; tt < 4; ++tt) {
                const int d = tt * 16 + n;
                half8 vf = *(const half8*)&Vt[buf][d * 64 + (((js << 2) | qd) ^ (d & 7)) * 8];
                Oacc[tt] = __builtin_amdgcn_mfma_f32_16x16x32_f16(pf, vf, Oacc[tt], 0, 0, 0);
            }
        }
        __builtin_amdgcn_s_setprio(0);
    };

    // valid chunk range (block-uniform): gk0 = s-128+64c in [0, T-64]
    const int cbeg = (s == 0) ? 2 : 0;
    const int cend = (s == T_SEQ - 128) ? 3 : 5;

    // ---- pipeline prologue (chunk cbeg loads already issued above) ----
    commitKV(0);                // one exposed vmcnt wait per WG
    prefetchKV(cbeg + 1);
    WG_BARRIER();               // buf 0 visible; next loads stay in flight

    #pragma unroll
    for (int cc = 0; cc < 6; ++cc) {
        const int c = cbeg + cc;
        if (c > cend) break;
        const int cur = cc & 1;
        if (c + 1 <= cend) commitKV(1 - cur);  // counted vmcnt wait only
        if (c + 2 <= cend) prefetchKV(c + 2);  // refill slot, issue early
        compute(cur, c);
        if (c < cend) WG_BARRIER();            // publish buf[1-cur]
    }

    // ---- epilogue: reduce l across quads, divide, store fp32 ----
    float lt = Lsum + __shfl_xor(Lsum, 16, 64);
    lt += __shfl_xor(lt, 32, 64);              // lanes with same n: full sum for query n
    #pragma unroll
    for (int rg = 0; rg < 4; ++rg) {
        const float lr = __shfl(lt, qd * 4 + rg, 64);  // L for this output row
        const float inv = 1.0f / lr;
        float* op = Op + (size_t)(s + 16 * w + qd * 4 + rg) * 64 + n;
        op[0]  = Oacc[0][rg] * inv;
        op[16] = Oacc[1][rg] * inv;
        op[32] = Oacc[2][rg] * inv;
        op[48] = Oacc[3][rg] * inv;
    }
}

extern "C" void kernel_launch(void* const* d_in, const int* in_sizes, int n_in,
                              void* d_out, int out_size, void* d_ws, size_t ws_size,
                              hipStream_t stream) {
    const float* q = (const float*)d_in[0];
    const float* k = (const float*)d_in[1];
    const float* v = (const float*)d_in[2];
    float* o = (float*)d_out;
    dim3 grid(T_SEQ / 128, NH, 2);
    dim3 block(512);
    local_attn_f16<<<grid, block, 0, stream>>>(q, k, v, o);
}

// Round 3
// 130.306 us; speedup vs baseline: 1.0008x; 1.0008x over previous
//
#include <hip/hip_runtime.h>

#define T_SEQ 4096
#define NH    12

typedef _Float16 half8  __attribute__((ext_vector_type(8)));
typedef _Float16 half4  __attribute__((ext_vector_type(4)));
typedef float    floatx4 __attribute__((ext_vector_type(4)));

// Sliding-window attention, window [gq-128, gq+128) ∩ [0,T).
// One WG = 128 query rows; 8 waves * 16 rows; grid = 768 = exactly 3 WG/CU
// (48 KB LDS * 3 = 144 KB/CU). Swapped QK^T (mfma(K,Q) -> S^T in regs):
// P spills as 4x ds_write_b64. Row-sum fused into exp pass; no ones-MFMA.
// ROLLED main loop (runtime LDS buf index, static register state) to keep
// VGPR <= 85 cap of __launch_bounds__(512,6) WITHOUT scratch spill --
// round-2 unrolled version spilled (VGPR=40, WRITE 2x output).
// Plane-grouped XCD map: xcd=bx&7 owns planes 3x..3x+2 (6MB K/V working
// set vs 9.2MB with the naive map) for L2 locality.
// Raw barrier: lgkmcnt drain only, NO vmcnt drain (T4) -- prefetch global
// loads stay in flight across it. setprio(1) around MFMA clusters (T5).
__global__ __launch_bounds__(512, 6) void local_attn_f16(
    const float* __restrict__ Qg, const float* __restrict__ Kg,
    const float* __restrict__ Vg, float* __restrict__ Og)
{
    // XOR-swizzled 16B-block layouts: element (row,x) at
    // row*64 + (((x>>3) ^ (row&7))*8) + (x&7)   [halves]
    __shared__ _Float16 Ks[2][64 * 64];  // K chunk  [key][d]
    __shared__ _Float16 Vt[2][64 * 64];  // V^T      [d][key]
    __shared__ _Float16 Ps[8][16 * 64];  // per-wave P [qrow][key]

    const int t    = threadIdx.x;
    const int w    = t >> 6;        // wave id 0..7
    const int lane = t & 63;
    const int n    = lane & 15;     // MFMA 16-index
    const int qd   = lane >> 4;     // quad 0..3

    // Plane-grouped XCD mapping: hardware round-robins wgid%8 = bx&7 across
    // XCDs (grid.x=32 ≡ 0 mod 8). XCD j gets planes 3j..3j+2, tiles
    // consecutive in dispatch order within a plane.
    const int bx = blockIdx.x;                    // 0..31
    const int u  = blockIdx.y + NH * blockIdx.z;  // 0..23
    const int plane = 3 * (bx & 7) + (u >> 3);    // 0..23
    const int tile  = (bx >> 3) + 4 * (u & 7);    // 0..31
    const int s     = tile << 7;                  // query tile start (128 rows)
    const size_t planeoff = (size_t)plane * (size_t)(T_SEQ * 64);

    const float* Qp = Qg + planeoff;
    const float* Kp = Kg + planeoff;
    const float* Vp = Vg + planeoff;
    float*       Op = Og + planeoff;

    // staging thread mappings (64-key chunk staged by all 512 threads)
    const int kr  = t >> 3;         // K row 0..63
    const int kbi = t & 7;          // 8-float block within row
    const int vd  = t & 63;         // V^T: this thread owns column d
    const int vjb = t >> 6;         // 8-key range per wave

    // ---- single prefetch slot (commit-first keeps exactly one slot live) ----
    floatx4 kp0, kp1;
    float   vp[8];

    auto prefetchKV = [&](int c) {
        const int gk0 = s - 128 + 64 * c;
        const float* kb = Kp + (size_t)(gk0 + kr) * 64 + kbi * 8;
        kp0 = *(const floatx4*)kb;
        kp1 = *(const floatx4*)(kb + 4);
        const float* vb = Vp + (size_t)(gk0 + vjb * 8) * 64 + vd;
        #pragma unroll
        for (int j = 0; j < 8; ++j)          // 8x coalesced 256B/wave
            vp[j] = vb[(size_t)j * 64];
    };

    auto commitKV = [&](int buf) {
        half8 hk, hv;
        #pragma unroll
        for (int i = 0; i < 4; ++i) {
            hk[i]     = (_Float16)kp0[i];
            hk[i + 4] = (_Float16)kp1[i];
        }
        #pragma unroll
        for (int i = 0; i < 8; ++i)
            hv[i] = (_Float16)vp[i];
        *(half8*)&Ks[buf][kr * 64 + (kbi ^ (kr & 7)) * 8] = hk;
        *(half8*)&Vt[buf][vd * 64 + (vjb ^ (vd & 7)) * 8] = hv;
    };

    // ---- preload Q B-fragments, scaled by log2(e)/sqrt(64) ----
    const int cbeg = (s == 0) ? 2 : 0;
    const int cend = (s == T_SEQ - 128) ? 3 : 5;

    prefetchKV(cbeg);               // issue first chunk's loads before Q loads
    half8 qf[2];
    {
        const float* qptr = Qp + (size_t)(s + 16 * w + n) * 64 + qd * 8;
        const float qscale = 0.125f * 1.44269504088896340736f;
        #pragma unroll
        for (int ks = 0; ks < 2; ++ks) {
            floatx4 a = *(const floatx4*)(qptr + 32 * ks);
            floatx4 b = *(const floatx4*)(qptr + 32 * ks + 4);
            half8 h;
            #pragma unroll
            for (int i = 0; i < 4; ++i) {
                h[i]     = (_Float16)(a[i] * qscale);
                h[i + 4] = (_Float16)(b[i] * qscale);
            }
            qf[ks] = h;
        }
    }

    floatx4 Oacc[4] = {{0.f,0.f,0.f,0.f},{0.f,0.f,0.f,0.f},
                       {0.f,0.f,0.f,0.f},{0.f,0.f,0.f,0.f}};
    float Lsum = 0.f;

    // Raw barrier: publish LDS writes, do NOT drain vmcnt (T4).
    #define WG_BARRIER() do {                                        \
        __builtin_amdgcn_sched_barrier(0);                           \
        asm volatile("s_waitcnt lgkmcnt(0)" ::: "memory");           \
        __builtin_amdgcn_s_barrier();                                \
        __builtin_amdgcn_sched_barrier(0);                           \
    } while (0)

    _Float16* Pw = &Ps[w][0];

    auto compute = [&](int buf, int c) {
        const int wbase = 16 * w;
        // wave-uniform full-mask skip: waves 4-7 skip c=0, waves 0-3 skip c=5
        if (64 * c + 63 < wbase || 64 * c >= wbase + 271) return;

        // ---- S^T = K (Q*log2e)^T : 8 MFMAs; S^T[key=16tt+qd*4+rg][query=n] ----
        floatx4 acc[4] = {{0.f,0.f,0.f,0.f},{0.f,0.f,0.f,0.f},
                          {0.f,0.f,0.f,0.f},{0.f,0.f,0.f,0.f}};
        __builtin_amdgcn_s_setprio(1);
        #pragma unroll
        for (int ks = 0; ks < 2; ++ks) {
            #pragma unroll
            for (int tt = 0; tt < 4; ++tt) {
                const int key = tt * 16 + n;
                half8 kf = *(const half8*)&Ks[buf][key * 64 + (((ks << 2) | qd) ^ (key & 7)) * 8];
                acc[tt] = __builtin_amdgcn_mfma_f32_16x16x32_f16(kf, qf[ks], acc[tt], 0, 0, 0);
            }
        }
        __builtin_amdgcn_s_setprio(0);

        // ---- window masks: key kk valid iff 0 <= 64c+kk-qloc < 256 ----
        const int qloc = wbase + n;
        if (64 * c < wbase + 16) {               // lower edge crosses this wave
            const int tLo = qloc - 64 * c;       // kk < tLo -> invalid
            #pragma unroll
            for (int tt = 0; tt < 4; ++tt)
                #pragma unroll
                for (int rg = 0; rg < 4; ++rg)
                    if (tt * 16 + qd * 4 + rg < tLo) acc[tt][rg] = -1e30f;
        }
        if (64 * c >= wbase + 193) {             // upper edge crosses this wave
            const int tHi = qloc + 256 - 64 * c; // kk >= tHi -> invalid
            #pragma unroll
            for (int tt = 0; tt < 4; ++tt)
                #pragma unroll
                for (int rg = 0; rg < 4; ++rg)
                    if (tt * 16 + qd * 4 + rg >= tHi) acc[tt][rg] = -1e30f;
        }

        // ---- P = exp2(S'), accumulate row-sum, pack 4 keys -> ds_write_b64 ----
        #pragma unroll
        for (int tt = 0; tt < 4; ++tt) {
            float p0, p1, p2, p3;
            asm("v_exp_f32 %0, %1" : "=v"(p0) : "v"(acc[tt][0]));
            asm("v_exp_f32 %0, %1" : "=v"(p1) : "v"(acc[tt][1]));
            asm("v_exp_f32 %0, %1" : "=v"(p2) : "v"(acc[tt][2]));
            asm("v_exp_f32 %0, %1" : "=v"(p3) : "v"(acc[tt][3]));
            Lsum += (p0 + p1) + (p2 + p3);
            half4 pk;
            pk[0] = (_Float16)p0; pk[1] = (_Float16)p1;
            pk[2] = (_Float16)p2; pk[3] = (_Float16)p3;
            // keys k0=16tt+4qd..+3, query n: contiguous 8B (block 2tt+(qd>>1))
            *(half4*)&Pw[n * 64 + ((2 * tt + (qd >> 1)) ^ (n & 7)) * 8 + (qd & 1) * 4] = pk;
        }

        // Ps is per-wave: drain DS writes only, no WG barrier.
        asm volatile("s_waitcnt lgkmcnt(0)" ::: "memory");

        // ---- O += P V ----
        __builtin_amdgcn_s_setprio(1);
        #pragma unroll
        for (int js = 0; js < 2; ++js) {
            half8 pf = *(const half8*)&Pw[n * 64 + (((js << 2) | qd) ^ (n & 7)) * 8];
            #pragma unroll
            for (int tt = 0; tt < 4; ++tt) {
                const int d = tt * 16 + n;
                half8 vf = *(const half8*)&Vt[buf][d * 64 + (((js << 2) | qd) ^ (d & 7)) * 8];
                Oacc[tt] = __builtin_amdgcn_mfma_f32_16x16x32_f16(pf, vf, Oacc[tt], 0, 0, 0);
            }
        }
        __builtin_amdgcn_s_setprio(0);
    };

    // ---- pipeline prologue (chunk cbeg loads already issued above) ----
    commitKV(0);                    // one exposed vmcnt wait per WG
    prefetchKV(cbeg + 1);
    WG_BARRIER();                   // buf 0 visible; next loads stay in flight

    // ---- ROLLED main loop: one code copy keeps VGPR pressure low ----
    int cur = 0;
    #pragma unroll 1
    for (int c = cbeg; c <= cend; ++c) {
        if (c + 1 <= cend) commitKV(1 - cur);  // counted vmcnt wait only
        if (c + 2 <= cend) prefetchKV(c + 2);  // refill slot, issue early
        compute(cur, c);
        if (c < cend) WG_BARRIER();            // publish buf[1-cur]
        cur ^= 1;
    }

    // ---- epilogue: reduce l across quads, divide, store fp32 ----
    float lt = Lsum + __shfl_xor(Lsum, 16, 64);
    lt += __shfl_xor(lt, 32, 64);              // lanes with same n: full sum for query n
    #pragma unroll
    for (int rg = 0; rg < 4; ++rg) {
        const float lr = __shfl(lt, qd * 4 + rg, 64);  // L for this output row
        const float inv = 1.0f / lr;
        float* op = Op + (size_t)(s + 16 * w + qd * 4 + rg) * 64 + n;
        op[0]  = Oacc[0][rg] * inv;
        op[16] = Oacc[1][rg] * inv;
        op[32] = Oacc[2][rg] * inv;
        op[48] = Oacc[3][rg] * inv;
    }
}

extern "C" void kernel_launch(void* const* d_in, const int* in_sizes, int n_in,
                              void* d_out, int out_size, void* d_ws, size_t ws_size,
                              hipStream_t stream) {
    const float* q = (const float*)d_in[0];
    const float* k = (const float*)d_in[1];
    const float* v = (const float*)d_in[2];
    float* o = (float*)d_out;
    dim3 grid(T_SEQ / 128, NH, 2);
    dim3 block(512);
    local_attn_f16<<<grid, block, 0, stream>>>(q, k, v, o);
}